// Round 7
// baseline (1493.192 us; speedup 1.0000x reference)
//
#include <hip/hip_runtime.h>

typedef unsigned short u16;
typedef __attribute__((ext_vector_type(8))) short short8;
typedef __attribute__((ext_vector_type(4))) float f32x4;

#define T_TOKENS 4096
#define DMODEL   768
#define DFF      3072
#define NEXP     8
#define NVOCAB   32000

__device__ __forceinline__ u16 f2bf(float f) {
  unsigned u = __float_as_uint(f);
  u += 0x7FFFu + ((u >> 16) & 1u);
  return (u16)(u >> 16);
}

__device__ __forceinline__ void async_load16(const void* g, void* lds) {
  __builtin_amdgcn_global_load_lds((const __attribute__((address_space(1))) void*)g,
                                   (__attribute__((address_space(3))) void*)lds,
                                   16, 0, 0);
}

#define SBAR() __builtin_amdgcn_s_barrier()
#define VMCNT(n) asm volatile("s_waitcnt vmcnt(" #n ")")
#define LGKM(n)  asm volatile("s_waitcnt lgkmcnt(" #n ")")

// ---------------- embed + router ----------------
__global__ __launch_bounds__(256) void k_embed_router(
    const int* __restrict__ x, const float* __restrict__ emb,
    const float* __restrict__ gw, const float* __restrict__ gb,
    u16* __restrict__ tbf, float* __restrict__ gates)
{
  __shared__ float partial[4][NEXP];
  const int t = blockIdx.x;
  const int tok = x[t];
  const float* er = emb + (size_t)tok * DMODEL;
  float p[NEXP];
#pragma unroll
  for (int e = 0; e < NEXP; ++e) p[e] = 0.f;
#pragma unroll
  for (int i = 0; i < 3; ++i) {
    const int d = threadIdx.x + i * 256;
    const float v = er[d];
    tbf[(size_t)t * DMODEL + d] = f2bf(v);
#pragma unroll
    for (int e = 0; e < NEXP; ++e) p[e] += v * gw[d * NEXP + e];
  }
#pragma unroll
  for (int e = 0; e < NEXP; ++e)
#pragma unroll
    for (int m = 32; m >= 1; m >>= 1) p[e] += __shfl_xor(p[e], m);
  const int lane = threadIdx.x & 63, wv = threadIdx.x >> 6;
  if (lane == 0)
    for (int e = 0; e < NEXP; ++e) partial[wv][e] = p[e];
  __syncthreads();
  if (threadIdx.x == 0) {
    float l[NEXP];
    for (int e = 0; e < NEXP; ++e)
      l[e] = partial[0][e] + partial[1][e] + partial[2][e] + partial[3][e] + gb[e];
    int i0 = 0;
    for (int e = 1; e < NEXP; ++e) if (l[e] > l[i0]) i0 = e;
    int i1 = -1;
    for (int e = 0; e < NEXP; ++e) { if (e == i0) continue; if (i1 < 0 || l[e] > l[i1]) i1 = e; }
    const float w0 = 1.f / (1.f + expf(l[i1] - l[i0]));
    float g[NEXP];
    for (int e = 0; e < NEXP; ++e) g[e] = 0.f;
    g[i0] = w0; g[i1] = 1.f - w0;
    for (int e = 0; e < NEXP; ++e) gates[t * NEXP + e] = g[e];
  }
}

// ---------------- transpose + fp32->bf16 convert ----------------
__global__ __launch_bounds__(256) void k_transpose_cvt(
    const float* __restrict__ src, u16* __restrict__ dst, int R, int C)
{
  __shared__ float tile[32][33];
  const float* s = src + (size_t)blockIdx.z * R * C;
  u16* d = dst + (size_t)blockIdx.z * R * C;
  const int tx = threadIdx.x & 31, ty = threadIdx.x >> 5;
  const int c = blockIdx.x * 32 + tx;
#pragma unroll
  for (int i = 0; i < 4; ++i) {
    const int r = blockIdx.y * 32 + ty + i * 8;
    tile[ty + i * 8][tx] = s[(size_t)r * C + c];
  }
  __syncthreads();
  const int rr = blockIdx.y * 32 + tx;
#pragma unroll
  for (int i = 0; i < 4; ++i) {
    const int cc = blockIdx.x * 32 + ty + i * 8;
    d[(size_t)cc * R + rr] = f2bf(tile[tx][ty + i * 8]);
  }
}

// ---------------- dense MoE FFN GEMM (128^2, verified) ----------------
__global__ __launch_bounds__(256) void k_ffn(
    const u16* __restrict__ A, const u16* __restrict__ BT,
    const float* __restrict__ gates, const float* __restrict__ eb,
    u16* __restrict__ moe)
{
  __shared__ u16 aT[128 * 64];
  __shared__ u16 bT[128 * 64];
  __shared__ float gLds[128][NEXP];
  const int tid = threadIdx.x;
  const int wave = tid >> 6, lane = tid & 63;
  const int wm = wave >> 1, wn = wave & 1;
  const int kg = lane >> 4, fr = lane & 15;
  const int m0 = blockIdx.y * 128, n0 = blockIdx.x * 128;

  for (int i = tid; i < 128 * NEXP; i += 256)
    gLds[i >> 3][i & 7] = gates[(size_t)(m0 + (i >> 3)) * NEXP + (i & 7)];

  f32x4 macc[4][4] = {};

  for (int e = 0; e < NEXP; ++e) {
    const u16* Be = BT + (size_t)e * DFF * DMODEL;
    f32x4 acc[4][4] = {};
    for (int ks = 0; ks < DMODEL / 64; ++ks) {
      __syncthreads();
      const int kb = ks * 64;
#pragma unroll
      for (int it = 0; it < 4; ++it) {
        const int c = it * 256 + tid;
        const int m = c >> 3;
        const int slot = (c & 7) ^ (m & 7);
        async_load16(A + (size_t)(m0 + m) * DMODEL + kb + slot * 8,
                     &aT[(it * 256 + wave * 64) * 8]);
        async_load16(Be + (size_t)(n0 + m) * DMODEL + kb + slot * 8,
                     &bT[(it * 256 + wave * 64) * 8]);
      }
      __syncthreads();
#pragma unroll
      for (int kk = 0; kk < 2; ++kk) {
        short8 af[4], bf[4];
#pragma unroll
        for (int i = 0; i < 4; ++i) {
          const int am = wm * 64 + i * 16 + fr;
          const int kc = kk * 4 + kg;
          af[i] = *(const short8*)&aT[(am * 8 + (kc ^ (am & 7))) * 8];
          const int bn = wn * 64 + i * 16 + fr;
          bf[i] = *(const short8*)&bT[(bn * 8 + (kc ^ (bn & 7))) * 8];
        }
#pragma unroll
        for (int i = 0; i < 4; ++i)
#pragma unroll
          for (int j = 0; j < 4; ++j)
            acc[i][j] = __builtin_amdgcn_mfma_f32_16x16x32_bf16(af[i], bf[j], acc[i][j], 0, 0, 0);
      }
    }
#pragma unroll
    for (int j = 0; j < 4; ++j) {
      const int col = n0 + wn * 64 + j * 16 + fr;
      const float b = eb[e * DFF + col];
#pragma unroll
      for (int i = 0; i < 4; ++i)
#pragma unroll
        for (int r = 0; r < 4; ++r) {
          float v = acc[i][j][r] + b;
          v = v > 0.f ? v : 0.f;
          macc[i][j][r] += gLds[wm * 64 + i * 16 + kg * 4 + r][e] * v;
        }
    }
  }
#pragma unroll
  for (int i = 0; i < 4; ++i)
#pragma unroll
    for (int r = 0; r < 4; ++r) {
      const int row = m0 + wm * 64 + i * 16 + kg * 4 + r;
#pragma unroll
      for (int j = 0; j < 4; ++j) {
        const int col = n0 + wn * 64 + j * 16 + fr;
        moe[(size_t)row * DFF + col] = f2bf(macc[i][j][r]);
      }
    }
}

// ---------------- head GEMM: 256^2, faithful m201 8-phase template ----------------
// Per phase: {ds-read this phase's frags; stage 1 half-tile; [lgkm(8) if 12 reads];
// BAR; lgkm(0); sched_barrier; prio1; 16 MFMA; prio0; BAR}. No mid-phase vmcnt;
// VMCNT(6) only at P4-end. Early lgkm(0) makes all reads COMPLETE before BAR2,
// so next phase's DMA stage into the just-read region is write-after-read safe.
// Stage slots: P1(t):A(t+1)h1  P2(t):A(t+2)h0  P3(t):B(t+2)h0  P4(t):B(t+2)h1.
// vmcnt ledger (2 loads/slot), entering P1(t): outstanding
// [A(t+1)h0,B(t+1)h0,B(t+1)h1]=6; +P1..P4 adds 8 -> 14; VMCNT(6) at P4-end
// keeps the 3 newest (t+2) slots, drains all of tile t+1 before BAR. Tail:
// VMCNT(0) at t==NT-2 (only A(NT-1)* ,B(NT-1)* remain), none at t==NT-1.
__device__ __forceinline__ short8 frag(const u16* buf, int row, int kc) {
  return *(const short8*)(buf + (row * 8 + (kc ^ (row & 7))) * 8);
}

__global__ __launch_bounds__(512, 2) void k_head(
    const u16* __restrict__ A, const u16* __restrict__ BT,
    const float* __restrict__ bias, float* __restrict__ C)
{
  __shared__ u16 aL[2][256 * 64];
  __shared__ u16 bL[2][256 * 64];
  const int tid = threadIdx.x;
  const int lane = tid & 63, wave = tid >> 6;
  const int wm = wave >> 2, wn = wave & 3;         // 2 x 4 wave grid
  const int kg = lane >> 4, fr = lane & 15;
  const int wg = (int)blockIdx.x;
  const int swz = (wg & 7) * 250 + (wg >> 3);      // bijective XCD swizzle (2000=8*250)
  const int m0 = (swz & 15) * 256;
  const int n0 = (swz >> 4) * 256;
  const int K = DFF, NT = K / 64;                  // 48 tiles

  // hoisted per-thread staging descriptors
  size_t gAo[2], gBo[2]; int lAo[2], lBo[2];
#pragma unroll
  for (int i = 0; i < 2; ++i) {
    const int c = i * 512 + tid, rl = c >> 3, s = c & 7;
    const int rA = (rl & 63) + ((rl >> 6) << 7);   // A: in-strip rows, h adds 64
    const int gsA = s ^ (rA & 7);
    gAo[i] = (size_t)(m0 + rA) * K + gsA * 8;
    lAo[i] = rA * 64 + s * 8;
    const int rB = (rl & 31) + ((rl >> 5) << 6);   // B: in-strip rows, h adds 32
    const int gsB = s ^ (rB & 7);
    gBo[i] = (size_t)(n0 + rB) * K + gsB * 8;
    lBo[i] = rB * 64 + s * 8;
  }
  auto stageA = [&](int kb, u16* buf, int h) {
#pragma unroll
    for (int i = 0; i < 2; ++i)
      async_load16(A + gAo[i] + (size_t)(h * 64) * K + kb, buf + lAo[i] + h * 4096);
  };
  auto stageB = [&](int kb, u16* buf, int h) {
#pragma unroll
    for (int i = 0; i < 2; ++i)
      async_load16(BT + gBo[i] + (size_t)(h * 32) * K + kb, buf + lBo[i] + h * 2048);
  };

  f32x4 acc[8][4] = {};
  short8 af0[4][2], af1[4][2], bfl[2][2], bfh[2][2];

  // prologue: t0 {Ah0,Ah1,Bh0,Bh1} + t1 {Ah0,Bh0,Bh1}; drain t0; BAR
  stageA(0, aL[0], 0); stageA(0, aL[0], 1);
  stageB(0, bL[0], 0); stageB(0, bL[0], 1);
  stageA(64, aL[1], 0); stageB(64, bL[1], 0); stageB(64, bL[1], 1);
  VMCNT(6);
  __builtin_amdgcn_sched_barrier(0);
  SBAR();

  for (int t = 0; t < NT; ++t) {
    const int cur = t & 1;
    const u16* a_ = aL[cur];
    const u16* b_ = bL[cur];
    const int kb1 = (t + 1) * 64, kb2 = (t + 2) * 64;

    // ---- P1: read A0(8)+B0(4); stage A(t+1)h1; MFMA af0 x bfl ----
#pragma unroll
    for (int mi = 0; mi < 4; ++mi)
#pragma unroll
      for (int kk = 0; kk < 2; ++kk)
        af0[mi][kk] = frag(a_, wm * 128 + mi * 16 + fr, kk * 4 + kg);
#pragma unroll
    for (int ni = 0; ni < 2; ++ni)
#pragma unroll
      for (int kk = 0; kk < 2; ++kk)
        bfl[ni][kk] = frag(b_, wn * 64 + ni * 16 + fr, kk * 4 + kg);
    if (t + 1 < NT) stageA(kb1, aL[cur ^ 1], 1);
    LGKM(8);
    SBAR();
    LGKM(0);
    __builtin_amdgcn_sched_barrier(0);
    __builtin_amdgcn_s_setprio(1);
#pragma unroll
    for (int mi = 0; mi < 4; ++mi)
#pragma unroll
      for (int ni = 0; ni < 2; ++ni)
#pragma unroll
        for (int kk = 0; kk < 2; ++kk)
          acc[mi][ni] = __builtin_amdgcn_mfma_f32_16x16x32_bf16(af0[mi][kk], bfl[ni][kk], acc[mi][ni], 0, 0, 0);
    __builtin_amdgcn_s_setprio(0);
    SBAR();

    // ---- P2: read B1(4); stage A(t+2)h0; MFMA af0 x bfh ----
#pragma unroll
    for (int ni = 0; ni < 2; ++ni)
#pragma unroll
      for (int kk = 0; kk < 2; ++kk)
        bfh[ni][kk] = frag(b_, wn * 64 + 32 + ni * 16 + fr, kk * 4 + kg);
    if (t + 2 < NT) stageA(kb2, aL[cur], 0);
    SBAR();
    LGKM(0);
    __builtin_amdgcn_sched_barrier(0);
    __builtin_amdgcn_s_setprio(1);
#pragma unroll
    for (int mi = 0; mi < 4; ++mi)
#pragma unroll
      for (int ni = 0; ni < 2; ++ni)
#pragma unroll
        for (int kk = 0; kk < 2; ++kk)
          acc[mi][ni + 2] = __builtin_amdgcn_mfma_f32_16x16x32_bf16(af0[mi][kk], bfh[ni][kk], acc[mi][ni + 2], 0, 0, 0);
    __builtin_amdgcn_s_setprio(0);
    SBAR();

    // ---- P3: read A1(8); stage B(t+2)h0; MFMA af1 x bfl ----
#pragma unroll
    for (int mi = 0; mi < 4; ++mi)
#pragma unroll
      for (int kk = 0; kk < 2; ++kk)
        af1[mi][kk] = frag(a_, wm * 128 + 64 + mi * 16 + fr, kk * 4 + kg);
    if (t + 2 < NT) stageB(kb2, bL[cur], 0);
    SBAR();
    LGKM(0);
    __builtin_amdgcn_sched_barrier(0);
    __builtin_amdgcn_s_setprio(1);
#pragma unroll
    for (int mi = 0; mi < 4; ++mi)
#pragma unroll
      for (int ni = 0; ni < 2; ++ni)
#pragma unroll
        for (int kk = 0; kk < 2; ++kk)
          acc[mi + 4][ni] = __builtin_amdgcn_mfma_f32_16x16x32_bf16(af1[mi][kk], bfl[ni][kk], acc[mi + 4][ni], 0, 0, 0);
    __builtin_amdgcn_s_setprio(0);
    SBAR();

    // ---- P4: 0 reads; stage B(t+2)h1; MFMA af1 x bfh; VMCNT ----
    if (t + 2 < NT) stageB(kb2, bL[cur], 1);
    SBAR();
    __builtin_amdgcn_s_setprio(1);
#pragma unroll
    for (int mi = 0; mi < 4; ++mi)
#pragma unroll
      for (int ni = 0; ni < 2; ++ni)
#pragma unroll
        for (int kk = 0; kk < 2; ++kk)
          acc[mi + 4][ni + 2] = __builtin_amdgcn_mfma_f32_16x16x32_bf16(af1[mi][kk], bfh[ni][kk], acc[mi + 4][ni + 2], 0, 0, 0);
    __builtin_amdgcn_s_setprio(0);
    if (t < NT - 2) { VMCNT(6); } else if (t == NT - 2) { VMCNT(0); }
    __builtin_amdgcn_sched_barrier(0);
    SBAR();
  }

  // epilogue: non-temporal stores
#pragma unroll
  for (int ni = 0; ni < 4; ++ni) {
    const int col = n0 + wn * 64 + ni * 16 + fr;
    const float b = bias[col];
#pragma unroll
    for (int mi = 0; mi < 8; ++mi) {
      const int row = m0 + wm * 128 + (mi >> 2) * 64 + (mi & 3) * 16 + kg * 4;
#pragma unroll
      for (int r = 0; r < 4; ++r)
        __builtin_nontemporal_store(acc[mi][ni][r] + b,
                                    &C[(size_t)(row + r) * NVOCAB + col]);
    }
  }
}

extern "C" void kernel_launch(void* const* d_in, const int* in_sizes, int n_in,
                              void* d_out, int out_size, void* d_ws, size_t ws_size,
                              hipStream_t stream) {
  const int*   x     = (const int*)d_in[0];
  const float* emb   = (const float*)d_in[1];
  const float* gw    = (const float*)d_in[2];
  const float* gb    = (const float*)d_in[3];
  const float* expw  = (const float*)d_in[4];
  const float* expb  = (const float*)d_in[5];
  const float* headw = (const float*)d_in[6];
  const float* headb = (const float*)d_in[7];
  float* out = (float*)d_out;

  char* ws = (char*)d_ws;
  size_t off = 0;
  auto alloc = [&](size_t bytes) { size_t r = off; off += (bytes + 255) & ~(size_t)255; return r; };
  u16*   tbf    = (u16*)(ws + alloc((size_t)T_TOKENS * DMODEL * 2));
  float* gates  = (float*)(ws + alloc((size_t)T_TOKENS * NEXP * 4));
  u16*   expwT  = (u16*)(ws + alloc((size_t)NEXP * DFF * DMODEL * 2));
  u16*   headwT = (u16*)(ws + alloc((size_t)NVOCAB * DFF * 2));
  u16*   moe    = (u16*)(ws + alloc((size_t)T_TOKENS * DFF * 2));

  k_embed_router<<<T_TOKENS, 256, 0, stream>>>(x, emb, gw, gb, tbf, gates);
  k_transpose_cvt<<<dim3(DFF / 32, DMODEL / 32, NEXP), 256, 0, stream>>>(expw, expwT, DMODEL, DFF);
  k_transpose_cvt<<<dim3(NVOCAB / 32, DFF / 32, 1), 256, 0, stream>>>(headw, headwT, DFF, NVOCAB);
  k_ffn<<<dim3(DFF / 128, T_TOKENS / 128), 256, 0, stream>>>(tbf, expwT, gates, expb, moe);
  k_head<<<(T_TOKENS / 256) * (NVOCAB / 256), 512, 0, stream>>>(moe, headwT, headb, out);
}

// Round 9
// 1245.946 us; speedup vs baseline: 1.1984x; 1.1984x over previous
//
#include <hip/hip_runtime.h>

typedef unsigned short u16;
typedef __attribute__((ext_vector_type(8))) short short8;
typedef __attribute__((ext_vector_type(4))) float f32x4;

#define T_TOKENS 4096
#define DMODEL   768
#define DFF      3072
#define NEXP     8
#define NVOCAB   32000

__device__ __forceinline__ u16 f2bf(float f) {
  unsigned u = __float_as_uint(f);
  u += 0x7FFFu + ((u >> 16) & 1u);
  return (u16)(u >> 16);
}
__device__ __forceinline__ float bf2f(u16 b) {
  return __uint_as_float(((unsigned)b) << 16);
}

__device__ __forceinline__ void async_load16(const void* g, void* lds) {
  __builtin_amdgcn_global_load_lds((const __attribute__((address_space(1))) void*)g,
                                   (__attribute__((address_space(3))) void*)lds, 16, 0, 0);
}

#define SBAR() __builtin_amdgcn_s_barrier()
#define VMCNT(n) asm volatile("s_waitcnt vmcnt(" #n ")")

// ---------------- embed + router + top2 list build ----------------
__global__ __launch_bounds__(256) void k_embed_router(
    const int* __restrict__ x, const float* __restrict__ emb,
    const float* __restrict__ gw, const float* __restrict__ gb,
    u16* __restrict__ tbf, int* __restrict__ counts,
    int* __restrict__ tlist, float* __restrict__ wlist)
{
  __shared__ float partial[4][NEXP];
  const int t = blockIdx.x;
  const int tok = x[t];
  const float* er = emb + (size_t)tok * DMODEL;
  float p[NEXP];
#pragma unroll
  for (int e = 0; e < NEXP; ++e) p[e] = 0.f;
#pragma unroll
  for (int i = 0; i < 3; ++i) {
    const int d = threadIdx.x + i * 256;
    const float v = er[d];
    tbf[(size_t)t * DMODEL + d] = f2bf(v);
#pragma unroll
    for (int e = 0; e < NEXP; ++e) p[e] += v * gw[d * NEXP + e];
  }
#pragma unroll
  for (int e = 0; e < NEXP; ++e)
#pragma unroll
    for (int m = 32; m >= 1; m >>= 1) p[e] += __shfl_xor(p[e], m);
  const int lane = threadIdx.x & 63, wv = threadIdx.x >> 6;
  if (lane == 0)
    for (int e = 0; e < NEXP; ++e) partial[wv][e] = p[e];
  __syncthreads();
  if (threadIdx.x == 0) {
    float l[NEXP];
    for (int e = 0; e < NEXP; ++e)
      l[e] = partial[0][e] + partial[1][e] + partial[2][e] + partial[3][e] + gb[e];
    int i0 = 0;
    for (int e = 1; e < NEXP; ++e) if (l[e] > l[i0]) i0 = e;   // ties: first (jax)
    int i1 = -1;
    for (int e = 0; e < NEXP; ++e) { if (e == i0) continue; if (i1 < 0 || l[e] > l[i1]) i1 = e; }
    const float w0 = 1.f / (1.f + expf(l[i1] - l[i0]));
    // slot 0 -> expert i0 weight w0 ; slot 1 -> expert i1 weight 1-w0
    int p0 = atomicAdd(&counts[0 * NEXP + i0], 1);
    tlist[(0 * NEXP + i0) * T_TOKENS + p0] = t;
    wlist[(0 * NEXP + i0) * T_TOKENS + p0] = w0;
    int p1 = atomicAdd(&counts[1 * NEXP + i1], 1);
    tlist[(1 * NEXP + i1) * T_TOKENS + p1] = t;
    wlist[(1 * NEXP + i1) * T_TOKENS + p1] = 1.f - w0;
  }
}

// ---------------- transpose + fp32->bf16 convert ----------------
__global__ __launch_bounds__(256) void k_transpose_cvt(
    const float* __restrict__ src, u16* __restrict__ dst, int R, int C)
{
  __shared__ float tile[32][33];
  const float* s = src + (size_t)blockIdx.z * R * C;
  u16* d = dst + (size_t)blockIdx.z * R * C;
  const int tx = threadIdx.x & 31, ty = threadIdx.x >> 5;
  const int c = blockIdx.x * 32 + tx;
#pragma unroll
  for (int i = 0; i < 4; ++i) {
    const int r = blockIdx.y * 32 + ty + i * 8;
    tile[ty + i * 8][tx] = s[(size_t)r * C + c];
  }
  __syncthreads();
  const int rr = blockIdx.y * 32 + tx;
#pragma unroll
  for (int i = 0; i < 4; ++i) {
    const int cc = blockIdx.x * 32 + ty + i * 8;
    d[(size_t)cc * R + rr] = f2bf(tile[tx][ty + i * 8]);
  }
}

// ---------------- sparse MoE FFN: one slot (gathered 128^2 GEMM) ----------------
// Grid: x=fblock(24), y=mblock(32), z=expert(8). Early-exit if mb*128 >= cnt.
// A rows gathered via tlist (per-lane global src for global_load_lds is legal).
// SLOT1 reads-adds-writes moe (unique writer per (t,col) within a kernel;
// slot0 covers every token exactly once so moe is fully initialized).
template <int SLOT1>
__global__ __launch_bounds__(256) void k_ffn_slot(
    const u16* __restrict__ tbf, const u16* __restrict__ BT,
    const float* __restrict__ eb, const int* __restrict__ counts,
    const int* __restrict__ tlist, const float* __restrict__ wlist,
    u16* __restrict__ moe)
{
  const int e = blockIdx.z;
  const int cnt = counts[SLOT1 * NEXP + e];
  const int mb = blockIdx.y;
  if (mb * 128 >= cnt) return;
  const int base = (SLOT1 * NEXP + e) * T_TOKENS + mb * 128;
  const int lim = cnt - mb * 128;                 // valid rows in this tile (1..128)

  __shared__ u16 aT[128 * 64];
  __shared__ u16 bT[128 * 64];
  const int tid = threadIdx.x;
  const int wave = tid >> 6, lane = tid & 63;
  const int wm = wave >> 1, wn = wave & 1;
  const int kg = lane >> 4, fr = lane & 15;
  const int n0 = blockIdx.x * 128;
  const u16* Be = BT + (size_t)e * DFF * DMODEL;

  // staging token ids (4 rows per thread), clamped to last valid entry
  int tokm[4];
#pragma unroll
  for (int it = 0; it < 4; ++it) {
    const int m = (it * 256 + tid) >> 3;
    tokm[it] = tlist[base + (m < lim ? m : lim - 1)];
  }

  f32x4 acc[4][4] = {};
  for (int ks = 0; ks < DMODEL / 64; ++ks) {
    __syncthreads();
    const int kb = ks * 64;
#pragma unroll
    for (int it = 0; it < 4; ++it) {
      const int c = it * 256 + tid;
      const int m = c >> 3;
      const int slot = (c & 7) ^ (m & 7);
      async_load16(tbf + (size_t)tokm[it] * DMODEL + kb + slot * 8,
                   &aT[(it * 256 + wave * 64) * 8]);
      async_load16(Be + (size_t)(n0 + m) * DMODEL + kb + slot * 8,
                   &bT[(it * 256 + wave * 64) * 8]);
    }
    __syncthreads();
#pragma unroll
    for (int kk = 0; kk < 2; ++kk) {
      short8 af[4], bf[4];
#pragma unroll
      for (int i = 0; i < 4; ++i) {
        const int am = wm * 64 + i * 16 + fr;
        const int kc = kk * 4 + kg;
        af[i] = *(const short8*)&aT[(am * 8 + (kc ^ (am & 7))) * 8];
        const int bn = wn * 64 + i * 16 + fr;
        bf[i] = *(const short8*)&bT[(bn * 8 + (kc ^ (bn & 7))) * 8];
      }
#pragma unroll
      for (int i = 0; i < 4; ++i)
#pragma unroll
        for (int j = 0; j < 4; ++j)
          acc[i][j] = __builtin_amdgcn_mfma_f32_16x16x32_bf16(af[i], bf[j], acc[i][j], 0, 0, 0);
    }
  }

  // epilogue: per-row token/weight lookup, relu+bias, weighted (add for slot1)
  int trow[4][4]; float wrow[4][4];
#pragma unroll
  for (int i = 0; i < 4; ++i)
#pragma unroll
    for (int r = 0; r < 4; ++r) {
      const int row = wm * 64 + i * 16 + kg * 4 + r;
      if (row < lim) { trow[i][r] = tlist[base + row]; wrow[i][r] = wlist[base + row]; }
      else trow[i][r] = -1;
    }
#pragma unroll
  for (int j = 0; j < 4; ++j) {
    const int col = n0 + wn * 64 + j * 16 + fr;
    const float b = eb[e * DFF + col];
#pragma unroll
    for (int i = 0; i < 4; ++i)
#pragma unroll
      for (int r = 0; r < 4; ++r) {
        if (trow[i][r] < 0) continue;
        float v = acc[i][j][r] + b;
        v = v > 0.f ? v : 0.f;
        v *= wrow[i][r];
        u16* dst = &moe[(size_t)trow[i][r] * DFF + col];
        if (SLOT1) v += bf2f(*dst);
        *dst = f2bf(v);
      }
  }
}

// ---------------- head GEMM: 256^2 tile, 16x16x32, pipelined 4-phase (R6 best) ----------------
__device__ __forceinline__ short8 frag(const u16* buf, int row, int kc) {
  return *(const short8*)(buf + (row * 8 + (kc ^ (row & 7))) * 8);
}

__global__ __launch_bounds__(512, 2) void k_head(
    const u16* __restrict__ A, const u16* __restrict__ BT,
    const float* __restrict__ bias, float* __restrict__ C)
{
  __shared__ u16 aL[2][256 * 64];
  __shared__ u16 bL[2][256 * 64];
  const int tid = threadIdx.x;
  const int lane = tid & 63, wave = tid >> 6;
  const int wm = wave >> 2, wn = wave & 3;         // 2 x 4 wave grid
  const int kg = lane >> 4, fr = lane & 15;
  const int wg = (int)blockIdx.x;
  const int swz = (wg & 7) * 250 + (wg >> 3);      // bijective XCD swizzle (2000=8*250)
  const int m0 = (swz & 15) * 256;
  const int n0 = (swz >> 4) * 256;
  const int K = DFF, NT = K / 64;                  // 48 tiles

  size_t gAo[2], gBo[2]; int lAo[2], lBo[2];
#pragma unroll
  for (int i = 0; i < 2; ++i) {
    const int c = i * 512 + tid, rl = c >> 3, s = c & 7;
    const int rA = (rl & 63) + ((rl >> 6) << 7);
    const int gsA = s ^ (rA & 7);
    gAo[i] = (size_t)(m0 + rA) * K + gsA * 8;
    lAo[i] = rA * 64 + s * 8;
    const int rB = (rl & 31) + ((rl >> 5) << 6);
    const int gsB = s ^ (rB & 7);
    gBo[i] = (size_t)(n0 + rB) * K + gsB * 8;
    lBo[i] = rB * 64 + s * 8;
  }
  auto stageA = [&](int kb, u16* buf, int h) {
#pragma unroll
    for (int i = 0; i < 2; ++i)
      async_load16(A + gAo[i] + (size_t)(h * 64) * K + kb, buf + lAo[i] + h * 4096);
  };
  auto stageB = [&](int kb, u16* buf, int h) {
#pragma unroll
    for (int i = 0; i < 2; ++i)
      async_load16(BT + gBo[i] + (size_t)(h * 32) * K + kb, buf + lBo[i] + h * 2048);
  };

  f32x4 acc[8][4] = {};
  short8 af0[4][2], af1[4][2], bfl[2][2], bfh[2][2];

  stageA(0, aL[0], 0); stageA(0, aL[0], 1);
  stageB(0, bL[0], 0); stageB(0, bL[0], 1);
  stageA(64, aL[1], 0); stageB(64, bL[1], 0); stageA(64, aL[1], 1);
  VMCNT(6);
  __builtin_amdgcn_sched_barrier(0);
  SBAR();
#pragma unroll
  for (int mi = 0; mi < 4; ++mi)
#pragma unroll
    for (int kk = 0; kk < 2; ++kk)
      af0[mi][kk] = frag(aL[0], wm * 128 + mi * 16 + fr, kk * 4 + kg);
#pragma unroll
  for (int ni = 0; ni < 2; ++ni)
#pragma unroll
    for (int kk = 0; kk < 2; ++kk)
      bfl[ni][kk] = frag(bL[0], wn * 64 + ni * 16 + fr, kk * 4 + kg);

  for (int t = 0; t < NT; ++t) {
    const int cur = t & 1;
    const u16* a_ = aL[cur];
    const u16* b_ = bL[cur];
    u16* aw = aL[cur];
    u16* bw = bL[cur];
    const u16* an = aL[cur ^ 1];
    const u16* bn = bL[cur ^ 1];
    const int kb1 = (t + 1) * 64, kb2 = (t + 2) * 64;

    // ---- P1: pre = bfh(t) + stage bL[t+1]h1; MFMA af0 x bfl ----
#pragma unroll
    for (int ni = 0; ni < 2; ++ni)
#pragma unroll
      for (int kk = 0; kk < 2; ++kk)
        bfh[ni][kk] = frag(b_, wn * 64 + 32 + ni * 16 + fr, kk * 4 + kg);
    if (t + 1 < NT) stageB(kb1, bL[cur ^ 1], 1);
    __builtin_amdgcn_s_setprio(1);
#pragma unroll
    for (int mi = 0; mi < 4; ++mi)
#pragma unroll
      for (int ni = 0; ni < 2; ++ni)
#pragma unroll
        for (int kk = 0; kk < 2; ++kk)
          acc[mi][ni] = __builtin_amdgcn_mfma_f32_16x16x32_bf16(af0[mi][kk], bfl[ni][kk], acc[mi][ni], 0, 0, 0);
    __builtin_amdgcn_s_setprio(0);
    SBAR();

    // ---- P2: pre = af1(t) + stage aL[t+2]h0; MFMA af0 x bfh ----
#pragma unroll
    for (int mi = 0; mi < 4; ++mi)
#pragma unroll
      for (int kk = 0; kk < 2; ++kk)
        af1[mi][kk] = frag(a_, wm * 128 + 64 + mi * 16 + fr, kk * 4 + kg);
    if (t + 2 < NT) stageA(kb2, aw, 0);
    __builtin_amdgcn_s_setprio(1);
#pragma unroll
    for (int mi = 0; mi < 4; ++mi)
#pragma unroll
      for (int ni = 0; ni < 2; ++ni)
#pragma unroll
        for (int kk = 0; kk < 2; ++kk)
          acc[mi][ni + 2] = __builtin_amdgcn_mfma_f32_16x16x32_bf16(af0[mi][kk], bfh[ni][kk], acc[mi][ni + 2], 0, 0, 0);
    __builtin_amdgcn_s_setprio(0);
    if (t < NT - 2) { VMCNT(8); } else if (t == NT - 2) { VMCNT(6); }
    __builtin_amdgcn_sched_barrier(0);
    SBAR();

    // ---- P3: pre = af0(t+1) + stage bL[t+2]h0; MFMA af1 x bfl ----
    if (t + 1 < NT) {
#pragma unroll
      for (int mi = 0; mi < 4; ++mi)
#pragma unroll
        for (int kk = 0; kk < 2; ++kk)
          af0[mi][kk] = frag(an, wm * 128 + mi * 16 + fr, kk * 4 + kg);
    }
    if (t + 2 < NT) stageB(kb2, bw, 0);
    __builtin_amdgcn_s_setprio(1);
#pragma unroll
    for (int mi = 0; mi < 4; ++mi)
#pragma unroll
      for (int ni = 0; ni < 2; ++ni)
#pragma unroll
        for (int kk = 0; kk < 2; ++kk)
          acc[mi + 4][ni] = __builtin_amdgcn_mfma_f32_16x16x32_bf16(af1[mi][kk], bfl[ni][kk], acc[mi + 4][ni], 0, 0, 0);
    __builtin_amdgcn_s_setprio(0);
    if (t < NT - 2) { VMCNT(8); } else if (t == NT - 2) { VMCNT(4); }
    __builtin_amdgcn_sched_barrier(0);
    SBAR();

    // ---- P4: pre = bfl(t+1) + stage aL[t+2]h1; MFMA af1 x bfh ----
    if (t + 1 < NT) {
#pragma unroll
      for (int ni = 0; ni < 2; ++ni)
#pragma unroll
        for (int kk = 0; kk < 2; ++kk)
          bfl[ni][kk] = frag(bn, wn * 64 + ni * 16 + fr, kk * 4 + kg);
    }
    if (t + 2 < NT) stageA(kb2, aw, 1);
    __builtin_amdgcn_s_setprio(1);
#pragma unroll
    for (int mi = 0; mi < 4; ++mi)
#pragma unroll
      for (int ni = 0; ni < 2; ++ni)
#pragma unroll
        for (int kk = 0; kk < 2; ++kk)
          acc[mi + 4][ni + 2] = __builtin_amdgcn_mfma_f32_16x16x32_bf16(af1[mi][kk], bfh[ni][kk], acc[mi + 4][ni + 2], 0, 0, 0);
    __builtin_amdgcn_s_setprio(0);
    if (t < NT - 2) { VMCNT(6); } else if (t == NT - 2) { VMCNT(0); }
    __builtin_amdgcn_sched_barrier(0);
    SBAR();
  }

  // epilogue: non-temporal stores
#pragma unroll
  for (int ni = 0; ni < 4; ++ni) {
    const int col = n0 + wn * 64 + ni * 16 + fr;
    const float b = bias[col];
#pragma unroll
    for (int mi = 0; mi < 8; ++mi) {
      const int row = m0 + wm * 128 + (mi >> 2) * 64 + (mi & 3) * 16 + kg * 4;
#pragma unroll
      for (int r = 0; r < 4; ++r)
        __builtin_nontemporal_store(acc[mi][ni][r] + b,
                                    &C[(size_t)(row + r) * NVOCAB + col]);
    }
  }
}

extern "C" void kernel_launch(void* const* d_in, const int* in_sizes, int n_in,
                              void* d_out, int out_size, void* d_ws, size_t ws_size,
                              hipStream_t stream) {
  const int*   x     = (const int*)d_in[0];
  const float* emb   = (const float*)d_in[1];
  const float* gw    = (const float*)d_in[2];
  const float* gb    = (const float*)d_in[3];
  const float* expw  = (const float*)d_in[4];
  const float* expb  = (const float*)d_in[5];
  const float* headw = (const float*)d_in[6];
  const float* headb = (const float*)d_in[7];
  float* out = (float*)d_out;

  char* ws = (char*)d_ws;
  size_t off = 0;
  auto alloc = [&](size_t bytes) { size_t r = off; off += (bytes + 255) & ~(size_t)255; return r; };
  u16*   tbf    = (u16*)(ws + alloc((size_t)T_TOKENS * DMODEL * 2));
  int*   counts = (int*)(ws + alloc(2 * NEXP * 4));
  int*   tlist  = (int*)(ws + alloc((size_t)2 * NEXP * T_TOKENS * 4));
  float* wlist  = (float*)(ws + alloc((size_t)2 * NEXP * T_TOKENS * 4));
  u16*   expwT  = (u16*)(ws + alloc((size_t)NEXP * DFF * DMODEL * 2));
  u16*   headwT = (u16*)(ws + alloc((size_t)NVOCAB * DFF * 2));
  u16*   moe    = (u16*)(ws + alloc((size_t)T_TOKENS * DFF * 2));

  hipMemsetAsync(counts, 0, 2 * NEXP * 4, stream);
  k_embed_router<<<T_TOKENS, 256, 0, stream>>>(x, emb, gw, gb, tbf, counts, tlist, wlist);
  k_transpose_cvt<<<dim3(DFF / 32, DMODEL / 32, NEXP), 256, 0, stream>>>(expw, expwT, DMODEL, DFF);
  k_transpose_cvt<<<dim3(NVOCAB / 32, DFF / 32, 1), 256, 0, stream>>>(headw, headwT, DFF, NVOCAB);
  k_ffn_slot<0><<<dim3(DFF / 128, T_TOKENS / 128, NEXP), 256, 0, stream>>>(
      tbf, expwT, expb, counts, tlist, wlist, moe);
  k_ffn_slot<1><<<dim3(DFF / 128, T_TOKENS / 128, NEXP), 256, 0, stream>>>(
      tbf, expwT, expb, counts, tlist, wlist, moe);
  k_head<<<(T_TOKENS / 256) * (NVOCAB / 256), 512, 0, stream>>>(moe, headwT, headb, out);
}